// Round 3
// baseline (228.571 us; speedup 1.0000x reference)
//
#include <hip/hip_runtime.h>
#include <math.h>

// IdealScore: B=16, N=10000, D=3072, fp32.
//   arg[b][n] = (at/bt2)*dot(x_b, img_n) - ((1-sval)/(2*sval))*||img_n||^2
//   (x_sq dropped: softmax shift-invariant per row)
//   w = softmax_n(arg); mix = w @ imgs; out = (at*mix - x)/bt2
//
// Near-one-hot softmax (arg std ~88): rows with arg < m-40 have weight
// <= 4e-18 -> sparse gather pass 2 over the ~1-5 surviving rows per b.
//
// R3: k1 split D across 2 block-groups (occupancy 2.4 -> ~4.9 waves/SIMD,
// round-2 profile showed latency-bound at Occ=23%), x staged in LDS
// (round-2: 16/20 VMEM per chunk were x re-loads missing L1).
#define BB 16
#define NN 10000
#define DD 3072
#define DSPLIT 2
#define DSEG (DD / DSPLIT)       // 1536
#define DC 256                    // chunk floats
#define SEL_CUT 40.0f

// ---- K1: partial dot + partial isq over one D-segment ----
// grid (625, 2) x 256 thr (4 waves). Wave w owns rows n0..n0+3; lanes cover
// a 256-float chunk (float4 each, coalesced). x chunk staged in LDS.
__global__ __launch_bounds__(256) void k1_partial(
    const float* __restrict__ x, const float* __restrict__ images,
    float* __restrict__ pd, float* __restrict__ pisq)
{
  __shared__ float xs[BB * DC];              // 16 KB
  const int t = threadIdx.x;
  const int lane = t & 63;
  const int wave = t >> 6;
  const int q = blockIdx.y;
  const int n0 = blockIdx.x * 16 + wave * 4; // 625*16 = 10000 exactly
  const int dbase = q * DSEG;

  float dotv[4][BB];
  float isq[4];
#pragma unroll
  for (int r = 0; r < 4; ++r) {
    isq[r] = 0.f;
#pragma unroll
    for (int b = 0; b < BB; ++b) dotv[r][b] = 0.f;
  }

#pragma unroll 1
  for (int c = 0; c < DSEG / DC; ++c) {
    __syncthreads();
    // stage x[:, dbase + c*256 .. +255]: 4096 floats = 1024 float4
#pragma unroll
    for (int k = 0; k < 4; ++k) {
      int f = t + 256 * k;                   // float4 index 0..1023
      int row = f >> 6;                      // 64 float4 per row
      int col = (f & 63) << 2;
      *(float4*)&xs[row * DC + col] =
          *(const float4*)&x[row * DD + dbase + c * DC + col];
    }
    __syncthreads();

    const int dg = dbase + c * DC + (lane << 2);
    float4 im[4];
#pragma unroll
    for (int r = 0; r < 4; ++r)
      im[r] = *(const float4*)&images[(size_t)(n0 + r) * DD + dg];
#pragma unroll
    for (int r = 0; r < 4; ++r)
      isq[r] += im[r].x * im[r].x + im[r].y * im[r].y +
                im[r].z * im[r].z + im[r].w * im[r].w;
#pragma unroll
    for (int b = 0; b < BB; ++b) {
      float4 xv = *(const float4*)&xs[b * DC + (lane << 2)];  // ds_read_b128
#pragma unroll
      for (int r = 0; r < 4; ++r)
        dotv[r][b] += im[r].x * xv.x + im[r].y * xv.y +
                      im[r].z * xv.z + im[r].w * xv.w;
    }
  }

  // 64-lane butterfly reductions
#pragma unroll
  for (int r = 0; r < 4; ++r) {
#pragma unroll
    for (int b = 0; b < BB; ++b) {
      float v = dotv[r][b];
#pragma unroll
      for (int m = 32; m >= 1; m >>= 1) v += __shfl_xor(v, m, 64);
      dotv[r][b] = v;
    }
    float v = isq[r];
#pragma unroll
    for (int m = 32; m >= 1; m >>= 1) v += __shfl_xor(v, m, 64);
    isq[r] = v;
  }

  if (lane < BB) {
#pragma unroll
    for (int r = 0; r < 4; ++r) {
      float dv = dotv[r][0];
#pragma unroll
      for (int b = 1; b < BB; ++b)
        if (lane == b) dv = dotv[r][b];      // cndmask chain
      pd[(size_t)q * BB * NN + lane * NN + (n0 + r)] = dv;
    }
  }
  if (lane < 4) {
    float v = isq[0];
#pragma unroll
    for (int r = 1; r < 4; ++r)
      if (lane == r) v = isq[r];
    pisq[q * NN + n0 + lane] = v;
  }
}

// ---- K2: combine partials -> args (registers) -> stats + select ----
// 16 blocks x 1024 thr. Thread t owns n = t, t+1024, ... (<=10 values);
// single global pass, reductions from registers.
__global__ __launch_bounds__(1024) void k2_select(
    const float* __restrict__ pd, const float* __restrict__ pisq,
    const float* __restrict__ svalp, int* __restrict__ cnt,
    int* __restrict__ idx, float* __restrict__ wv)
{
  __shared__ float red[16];
  __shared__ float mshared, lshared;
  const int b = blockIdx.x;
  const int t = threadIdx.x;
  const int lane = t & 63, wave = t >> 6;
  if (t == 0) cnt[b] = 0;                    // ws is poisoned 0xAA

  const float sval = *svalp;
  const float at = sqrtf(1.f - sval);
  const float c1 = at / sval;
  const float c2 = (1.f - sval) / (2.f * sval);

  float a[10];
#pragma unroll
  for (int i = 0; i < 10; ++i) {
    int n = t + (i << 10);
    if (n < NN) {
      float d0 = pd[b * NN + n];
      float d1 = pd[(size_t)BB * NN + b * NN + n];
      float s0 = pisq[n];
      float s1 = pisq[NN + n];
      a[i] = c1 * (d0 + d1) - c2 * (s0 + s1);
    } else {
      a[i] = -INFINITY;
    }
  }

  float mx = -INFINITY;
#pragma unroll
  for (int i = 0; i < 10; ++i) mx = fmaxf(mx, a[i]);
#pragma unroll
  for (int m = 32; m >= 1; m >>= 1) mx = fmaxf(mx, __shfl_xor(mx, m, 64));
  if (lane == 0) red[wave] = mx;
  __syncthreads();
  if (wave == 0) {
    float v = (lane < 16) ? red[lane] : -INFINITY;
#pragma unroll
    for (int m = 8; m >= 1; m >>= 1) v = fmaxf(v, __shfl_xor(v, m, 64));
    if (lane == 0) mshared = v;
  }
  __syncthreads();
  mx = mshared;

  float s = 0.f;
#pragma unroll
  for (int i = 0; i < 10; ++i) s += __expf(a[i] - mx);  // exp(-inf)=0
#pragma unroll
  for (int m = 32; m >= 1; m >>= 1) s += __shfl_xor(s, m, 64);
  if (lane == 0) red[wave] = s;
  __syncthreads();
  if (wave == 0) {
    float v = (lane < 16) ? red[lane] : 0.f;
#pragma unroll
    for (int m = 8; m >= 1; m >>= 1) v += __shfl_xor(v, m, 64);
    if (lane == 0) lshared = v;
  }
  __syncthreads();
  const float invl = 1.f / lshared;

#pragma unroll
  for (int i = 0; i < 10; ++i) {
    if (a[i] > mx - SEL_CUT) {               // ~1-5 hits per row
      int k = atomicAdd(&cnt[b], 1);
      idx[b * NN + k] = t + (i << 10);
      wv[b * NN + k] = __expf(a[i] - mx) * invl;
    }
  }
}

// ---- K3: sparse mix + fused final affine -> out ----
__global__ __launch_bounds__(256) void k3_sparse(
    const float* __restrict__ images, const float* __restrict__ x,
    const float* __restrict__ svalp, const int* __restrict__ cnt,
    const int* __restrict__ idx, const float* __restrict__ wv,
    float* __restrict__ out)
{
  const int b = blockIdx.y;
  const int d0 = blockIdx.x * 1024 + (threadIdx.x << 2);
  const int c = cnt[b];

  float4 acc = make_float4(0.f, 0.f, 0.f, 0.f);
  for (int j = 0; j < c; ++j) {
    int n = idx[b * NN + j];
    float w = wv[b * NN + j];
    float4 im = *(const float4*)&images[(size_t)n * DD + d0];
    acc.x += w * im.x; acc.y += w * im.y;
    acc.z += w * im.z; acc.w += w * im.w;
  }

  const float sval = *svalp;
  const float at = sqrtf(1.f - sval);
  const float inv_bt2 = 1.f / sval;
  float4 xv = *(const float4*)&x[b * DD + d0];
  float4 o;
  o.x = (at * acc.x - xv.x) * inv_bt2;
  o.y = (at * acc.y - xv.y) * inv_bt2;
  o.z = (at * acc.z - xv.z) * inv_bt2;
  o.w = (at * acc.w - xv.w) * inv_bt2;
  *(float4*)&out[b * DD + d0] = o;
}

extern "C" void kernel_launch(void* const* d_in, const int* in_sizes, int n_in,
                              void* d_out, int out_size, void* d_ws, size_t ws_size,
                              hipStream_t stream) {
  const float* x      = (const float*)d_in[0];
  const float* images = (const float*)d_in[1];
  const float* sval   = (const float*)d_in[2];
  float* out = (float*)d_out;
  float* ws  = (float*)d_ws;

  // ws layout (floats): pd[2*16*10000] | pisq[2*10000] | cnt[16]i | pad[16]
  //                     idx[16*10000]i | wv[16*10000]  -> 2.64 MB total
  float* pd   = ws;
  float* pisq = ws + 320000;
  int*   cnt  = (int*)(ws + 340000);
  int*   idx  = (int*)(ws + 340032);
  float* wv   = ws + 500032;

  hipLaunchKernelGGL(k1_partial, dim3(625, DSPLIT), dim3(256), 0, stream,
                     x, images, pd, pisq);
  hipLaunchKernelGGL(k2_select, dim3(16), dim3(1024), 0, stream,
                     pd, pisq, sval, cnt, idx, wv);
  hipLaunchKernelGGL(k3_sparse, dim3(3, 16), dim3(256), 0, stream,
                     images, x, sval, cnt, idx, wv, out);
}